// Round 10
// baseline (86.299 us; speedup 1.0000x reference)
//
#include <hip/hip_runtime.h>
#include <math.h>

#define DDIM 640
#define IDIM 640
#define TWO_I 1280
#define KSEL 4
#define NEXP 32
#define NTOK 64
#define NPAIR 256
#define EPSV 1e-5f
#define LIMIT 7.0f
#define CHUNK 16      // tokens per pass (in registers)
#define RC 8          // reduction-dim chunks
#define RLEN 80       // rows per chunk (640/8)

#define WAITVM(n) asm volatile("s_waitcnt vmcnt(" #n ")" ::: "memory")
#define RAWBAR() __builtin_amdgcn_s_barrier()
// aux=0: default caching (control, used for w2)
#define GLL(gp, lp)                                                            \
    __builtin_amdgcn_global_load_lds(                                          \
        (const __attribute__((address_space(1))) void*)(gp),                   \
        (__attribute__((address_space(3))) void*)(lp), 16, 0, 0)
// aux=18 = NT|SC1 (gfx94x cpol: SC0=1, NT=2, SC1=16): non-temporal device-scope
// streaming read — experiment: bypass L2/L3 allocation for the w1 stream.
#define GLLNT(gp, lp)                                                          \
    __builtin_amdgcn_global_load_lds(                                          \
        (const __attribute__((address_space(1))) void*)(gp),                   \
        (__attribute__((address_space(3))) void*)(lp), 16, 0, 18)

// ws layout (float elements):
//  tws    : [64][640]            @ 0         (40960)
//  hact   : [256][640]           @ 40960     (163840)
//  hpart  : [8][256][1280]       @ 204800    (2621440)
//  ew     : [256]                @ 2826240
//  counts : [32] (int)           @ 2826496
//  list   : [32][64] (int)       @ 2826528
//  pexp   : [256] (int)          @ 2828576

__global__ void k_rmsnorm(const float* __restrict__ x, const float* __restrict__ nw,
                          float* __restrict__ tws, int* __restrict__ counts) {
    const int t = blockIdx.x;
    const int tid = threadIdx.x;
    if (blockIdx.x == 0 && tid < NEXP) counts[tid] = 0;
    __shared__ float red[256];
    float s = 0.f;
    for (int d = tid; d < DDIM; d += 256) {
        float v = x[d * NTOK + t];
        s += v * v;
    }
    red[tid] = s;
    __syncthreads();
    for (int off = 128; off > 0; off >>= 1) {
        if (tid < off) red[tid] += red[tid + off];
        __syncthreads();
    }
    const float rs = 1.0f / sqrtf(red[0] * (1.0f / DDIM) + EPSV);
    for (int d = tid; d < DDIM; d += 256) {
        tws[t * DDIM + d] = x[d * NTOK + t] * rs * nw[d];
    }
}

__global__ void k_router(const float* __restrict__ tws, const float* __restrict__ gw,
                         const float* __restrict__ gb, float* __restrict__ ew,
                         int* __restrict__ counts, int* __restrict__ list,
                         int* __restrict__ pexp) {
    const int t = blockIdx.x;
    const int lane = threadIdx.x;
    __shared__ float lg[NEXP];
    if (lane < NEXP) {
        const float* g = gw + lane * DDIM;
        const float* tr = tws + t * DDIM;
        float acc = 0.f;
        for (int d = 0; d < DDIM; d += 4) {
            acc = fmaf(tr[d], g[d], acc);
            acc = fmaf(tr[d + 1], g[d + 1], acc);
            acc = fmaf(tr[d + 2], g[d + 2], acc);
            acc = fmaf(tr[d + 3], g[d + 3], acc);
        }
        lg[lane] = acc + gb[lane];
    }
    __syncthreads();
    if (lane == 0) {
        float vals[KSEL];
        int idx[KSEL];
        for (int k = 0; k < KSEL; ++k) {
            float best = -1e30f;
            int bi = 0;
            for (int e = 0; e < NEXP; ++e) {
                float v = lg[e];
                if (v > best) { best = v; bi = e; }
            }
            vals[k] = best;
            idx[k] = bi;
            lg[bi] = -1e30f;
        }
        const float m = vals[0];
        float ex[KSEL];
        float se = 0.f;
        for (int k = 0; k < KSEL; ++k) { ex[k] = __expf(vals[k] - m); se += ex[k]; }
        const float inv = 1.0f / se;
        for (int k = 0; k < KSEL; ++k) {
            const int p = t * KSEL + k;
            ew[p] = ex[k] * inv;
            pexp[p] = idx[k];
            const int slot = atomicAdd(&counts[idx[k]], 1);
            list[idx[k] * NTOK + slot] = p;
        }
    }
}

// grid (RC=8, NEXP=32) = 256 blocks, 1/CU. 320 threads (5 waves).
// w1 panel streamed sequentially via global_load_lds with NT|SC1 cache policy
// (the A/B experiment vs ffn2's default policy).
__global__ __launch_bounds__(320, 1) void k_ffn1(const float* __restrict__ tws,
                                                 const float* __restrict__ w1,
                                                 float* __restrict__ hpart,
                                                 const int* __restrict__ counts,
                                                 const int* __restrict__ list) {
    const int rc = blockIdx.x;
    const int e = blockIdx.y;
    const int cnt = counts[e];
    const int tid = threadIdx.x;
    const int wid = tid >> 6;
    const int lane = tid & 63;
    const int col0 = wid * 256 + lane * 4;   // 0..1279
    const int d0 = rc * RLEN;

    __shared__ float wlds[2][8 * TWO_I];   // 2 x 40 KB
    __shared__ float tl[CHUNK][RLEN];      // 5 KB

    const float* wpanel = w1 + (size_t)e * DDIM * TWO_I + (size_t)d0 * TWO_I;

    for (int c0 = 0; c0 < cnt; c0 += CHUNK) {
        int pid[CHUNK];
#pragma unroll
        for (int s = 0; s < CHUNK; ++s) {
            int ii = c0 + s;
            ii = (ii < cnt) ? ii : c0;  // pad: duplicate math, duplicate same-value store
            pid[s] = list[e * NTOK + ii];
        }
        __syncthreads();   // previous pass fully done before tl overwrite
#pragma unroll
        for (int s = 0; s < CHUNK; ++s)
            for (int d = tid; d < RLEN; d += 320)
                tl[s][d] = tws[(pid[s] >> 2) * DDIM + d0 + d];
        __syncthreads();

        float acc[CHUNK][4];
#pragma unroll
        for (int s = 0; s < CHUNK; ++s)
#pragma unroll
            for (int c = 0; c < 4; ++c) acc[s][c] = 0.f;

#pragma unroll
        for (int k = 0; k < 8; ++k)
            GLLNT(wpanel + wid * 2048 + k * 256 + lane * 4, &wlds[0][wid * 2048 + k * 256]);

        for (int t = 0; t < 10; ++t) {
            const int cur = t & 1;
            if (t + 1 < 10) {
                const int nxt = (t + 1) & 1;
                const float* gsrc = wpanel + (size_t)(t + 1) * 8 * TWO_I;
#pragma unroll
                for (int k = 0; k < 8; ++k)
                    GLLNT(gsrc + wid * 2048 + k * 256 + lane * 4, &wlds[nxt][wid * 2048 + k * 256]);
                WAITVM(8);
            } else {
                WAITVM(0);
            }
            RAWBAR();
#pragma unroll
            for (int r = 0; r < 8; ++r) {
                const float4 w = *reinterpret_cast<const float4*>(&wlds[cur][r * TWO_I + col0]);
                const int row = t * 8 + r;
#pragma unroll
                for (int s = 0; s < CHUNK; ++s) {
                    const float tv = tl[s][row];
                    acc[s][0] = fmaf(tv, w.x, acc[s][0]);
                    acc[s][1] = fmaf(tv, w.y, acc[s][1]);
                    acc[s][2] = fmaf(tv, w.z, acc[s][2]);
                    acc[s][3] = fmaf(tv, w.w, acc[s][3]);
                }
            }
            RAWBAR();
        }

#pragma unroll
        for (int s = 0; s < CHUNK; ++s) {
            float4 v = make_float4(acc[s][0], acc[s][1], acc[s][2], acc[s][3]);
            *reinterpret_cast<float4*>(&hpart[((size_t)rc * NPAIR + pid[s]) * TWO_I + col0]) = v;
        }
    }
}

// grid (256) x 256: reduce rc partials, add bias, activation -> hact
__global__ void k_reduce1(const float* __restrict__ hpart, const float* __restrict__ b1,
                          const int* __restrict__ pexp, float* __restrict__ hact) {
    const int p = blockIdx.x;
    const int e = pexp[p];
    for (int i = threadIdx.x; i < IDIM; i += 256) {
        float g = 0.f, l = 0.f;
#pragma unroll
        for (int rc = 0; rc < RC; ++rc) {
            g += hpart[((size_t)rc * NPAIR + p) * TWO_I + i];
            l += hpart[((size_t)rc * NPAIR + p) * TWO_I + i + IDIM];
        }
        float hg = fminf(g + b1[e * TWO_I + i], LIMIT);
        float hl = l + b1[e * TWO_I + IDIM + i];
        hl = fminf(fmaxf(hl, -LIMIT), LIMIT);
        const float sig = 1.0f / (1.0f + __expf(-1.702f * hg));
        hact[(size_t)p * IDIM + i] = hg * sig * (hl + 1.0f);
    }
}

// grid (RC=8, NEXP=32): control arm — identical staging with DEFAULT cache policy.
__global__ __launch_bounds__(320, 1) void k_ffn2(const float* __restrict__ hact,
                                                 const float* __restrict__ w2,
                                                 float* __restrict__ hpart2,
                                                 const int* __restrict__ counts,
                                                 const int* __restrict__ list) {
    const int rc = blockIdx.x;
    const int e = blockIdx.y;
    const int cnt = counts[e];
    const int tid = threadIdx.x;
    const int wid = tid >> 6;
    const int lane = tid & 63;
    const int col0 = tid * 2;                // 0..638
    const int i0 = rc * RLEN;

    __shared__ float wlds[2][16 * DDIM];   // 2 x 40 KB
    __shared__ float tl[CHUNK][RLEN];

    const float* wpanel = w2 + (size_t)e * IDIM * DDIM + (size_t)i0 * DDIM;

    for (int c0 = 0; c0 < cnt; c0 += CHUNK) {
        int pid[CHUNK];
#pragma unroll
        for (int s = 0; s < CHUNK; ++s) {
            int ii = c0 + s;
            ii = (ii < cnt) ? ii : c0;
            pid[s] = list[e * NTOK + ii];
        }
        __syncthreads();
#pragma unroll
        for (int s = 0; s < CHUNK; ++s)
            for (int d = tid; d < RLEN; d += 320)
                tl[s][d] = hact[(size_t)pid[s] * IDIM + i0 + d];
        __syncthreads();

        float acc[CHUNK][2];
#pragma unroll
        for (int s = 0; s < CHUNK; ++s) { acc[s][0] = 0.f; acc[s][1] = 0.f; }

#pragma unroll
        for (int k = 0; k < 8; ++k)
            GLL(wpanel + wid * 2048 + k * 256 + lane * 4, &wlds[0][wid * 2048 + k * 256]);

        for (int t = 0; t < 5; ++t) {
            const int cur = t & 1;
            if (t + 1 < 5) {
                const int nxt = (t + 1) & 1;
                const float* gsrc = wpanel + (size_t)(t + 1) * 16 * DDIM;
#pragma unroll
                for (int k = 0; k < 8; ++k)
                    GLL(gsrc + wid * 2048 + k * 256 + lane * 4, &wlds[nxt][wid * 2048 + k * 256]);
                WAITVM(8);
            } else {
                WAITVM(0);
            }
            RAWBAR();
#pragma unroll
            for (int r = 0; r < 16; ++r) {
                const float2 w = *reinterpret_cast<const float2*>(&wlds[cur][r * DDIM + col0]);
                const int row = t * 16 + r;
#pragma unroll
                for (int s = 0; s < CHUNK; ++s) {
                    const float hv = tl[s][row];
                    acc[s][0] = fmaf(hv, w.x, acc[s][0]);
                    acc[s][1] = fmaf(hv, w.y, acc[s][1]);
                }
            }
            RAWBAR();
        }

#pragma unroll
        for (int s = 0; s < CHUNK; ++s) {
            float2 v = make_float2(acc[s][0], acc[s][1]);
            *reinterpret_cast<float2*>(&hpart2[((size_t)rc * NPAIR + pid[s]) * DDIM + col0]) = v;
        }
    }
}

// grid (64) x 256: reduce rc partials of ffn2, add bias, weight by ew, sum k, residual
__global__ void k_final(const float* __restrict__ x, const float* __restrict__ hpart2,
                        const float* __restrict__ b2, const float* __restrict__ ew,
                        const int* __restrict__ pexp, float* __restrict__ out) {
    const int t = blockIdx.x;
    for (int d = threadIdx.x; d < DDIM; d += 256) {
        float v = x[d * NTOK + t];
#pragma unroll
        for (int k = 0; k < KSEL; ++k) {
            const int p = t * KSEL + k;
            const int e = pexp[p];
            float s = 0.f;
#pragma unroll
            for (int rc = 0; rc < RC; ++rc)
                s += hpart2[((size_t)rc * NPAIR + p) * DDIM + d];
            v += (s + b2[e * DDIM + d]) * ew[p];
        }
        out[d * NTOK + t] = v;
    }
}

extern "C" void kernel_launch(void* const* d_in, const int* in_sizes, int n_in,
                              void* d_out, int out_size, void* d_ws, size_t ws_size,
                              hipStream_t stream) {
    const float* x  = (const float*)d_in[0];
    const float* nw = (const float*)d_in[1];
    const float* gw = (const float*)d_in[2];
    const float* gb = (const float*)d_in[3];
    const float* w1 = (const float*)d_in[4];
    const float* b1 = (const float*)d_in[5];
    const float* w2 = (const float*)d_in[6];
    const float* b2 = (const float*)d_in[7];
    float* out = (float*)d_out;

    float* ws    = (float*)d_ws;
    float* tws   = ws;                    // 40960
    float* hact  = ws + 40960;            // 163840
    float* hpart = ws + 204800;           // 2621440 (ffn1), reused for ffn2
    float* ew    = ws + 2826240;          // 256
    int* counts  = (int*)(ws + 2826496);  // 32
    int* list    = (int*)(ws + 2826528);  // 2048
    int* pexp    = (int*)(ws + 2828576);  // 256

    hipLaunchKernelGGL(k_rmsnorm, dim3(NTOK), dim3(256), 0, stream, x, nw, tws, counts);
    hipLaunchKernelGGL(k_router, dim3(NTOK), dim3(64), 0, stream, tws, gw, gb, ew, counts, list, pexp);
    hipLaunchKernelGGL(k_ffn1, dim3(RC, NEXP), dim3(320), 0, stream, tws, w1, hpart, counts, list);
    hipLaunchKernelGGL(k_reduce1, dim3(NPAIR), dim3(256), 0, stream, hpart, b1, pexp, hact);
    hipLaunchKernelGGL(k_ffn2, dim3(RC, NEXP), dim3(320), 0, stream, hact, w2, hpart, counts, list);
    hipLaunchKernelGGL(k_final, dim3(NTOK), dim3(256), 0, stream, x, hpart, b2, ew, pexp, out);
}

// Round 11
// 80.763 us; speedup vs baseline: 1.0685x; 1.0685x over previous
//
#include <hip/hip_runtime.h>
#include <math.h>

#define DDIM 640
#define IDIM 640
#define TWO_I 1280
#define KSEL 4
#define NEXP 32
#define NTOK 64
#define NPAIR 256
#define EPSV 1e-5f
#define LIMIT 7.0f
#define CHUNK 16      // tokens per pass (in registers)
#define RC 8          // reduction-dim chunks
#define RLEN 80       // rows per chunk (640/8)

#define WAITVM(n) asm volatile("s_waitcnt vmcnt(" #n ")" ::: "memory")
#define RAWBAR() __builtin_amdgcn_s_barrier()
#define GLL(gp, lp)                                                            \
    __builtin_amdgcn_global_load_lds(                                          \
        (const __attribute__((address_space(1))) void*)(gp),                   \
        (__attribute__((address_space(3))) void*)(lp), 16, 0, 0)

// ws layout (float elements):
//  tws    : [64][640]            @ 0         (40960)
//  hact   : [256][640]           @ 40960     (163840)
//  hpart  : [8][256][1280]       @ 204800    (2621440)
//  ew     : [256]                @ 2826240
//  counts : [32] (int)           @ 2826496
//  list   : [32][64] (int)       @ 2826528
//  pexp   : [256] (int)          @ 2828576

__global__ void k_rmsnorm(const float* __restrict__ x, const float* __restrict__ nw,
                          float* __restrict__ tws, int* __restrict__ counts) {
    const int t = blockIdx.x;
    const int tid = threadIdx.x;
    if (blockIdx.x == 0 && tid < NEXP) counts[tid] = 0;
    __shared__ float red[256];
    float s = 0.f;
    for (int d = tid; d < DDIM; d += 256) {
        float v = x[d * NTOK + t];
        s += v * v;
    }
    red[tid] = s;
    __syncthreads();
    for (int off = 128; off > 0; off >>= 1) {
        if (tid < off) red[tid] += red[tid + off];
        __syncthreads();
    }
    const float rs = 1.0f / sqrtf(red[0] * (1.0f / DDIM) + EPSV);
    for (int d = tid; d < DDIM; d += 256) {
        tws[t * DDIM + d] = x[d * NTOK + t] * rs * nw[d];
    }
}

__global__ void k_router(const float* __restrict__ tws, const float* __restrict__ gw,
                         const float* __restrict__ gb, float* __restrict__ ew,
                         int* __restrict__ counts, int* __restrict__ list,
                         int* __restrict__ pexp) {
    const int t = blockIdx.x;
    const int lane = threadIdx.x;
    __shared__ float lg[NEXP];
    if (lane < NEXP) {
        const float* g = gw + lane * DDIM;
        const float* tr = tws + t * DDIM;
        float acc = 0.f;
        for (int d = 0; d < DDIM; d += 4) {
            acc = fmaf(tr[d], g[d], acc);
            acc = fmaf(tr[d + 1], g[d + 1], acc);
            acc = fmaf(tr[d + 2], g[d + 2], acc);
            acc = fmaf(tr[d + 3], g[d + 3], acc);
        }
        lg[lane] = acc + gb[lane];
    }
    __syncthreads();
    if (lane == 0) {
        float vals[KSEL];
        int idx[KSEL];
        for (int k = 0; k < KSEL; ++k) {
            float best = -1e30f;
            int bi = 0;
            for (int e = 0; e < NEXP; ++e) {
                float v = lg[e];
                if (v > best) { best = v; bi = e; }
            }
            vals[k] = best;
            idx[k] = bi;
            lg[bi] = -1e30f;
        }
        const float m = vals[0];
        float ex[KSEL];
        float se = 0.f;
        for (int k = 0; k < KSEL; ++k) { ex[k] = __expf(vals[k] - m); se += ex[k]; }
        const float inv = 1.0f / se;
        for (int k = 0; k < KSEL; ++k) {
            const int p = t * KSEL + k;
            ew[p] = ex[k] * inv;
            pexp[p] = idx[k];
            const int slot = atomicAdd(&counts[idx[k]], 1);
            list[idx[k] * NTOK + slot] = p;
        }
    }
}

// grid (RC=8, NEXP=32) = 256 blocks, 1/CU. 320 threads (5 waves).
// ROTATED tile walk: block (e,rc) starts its 10-tile stream at tile
// t0=(3e+7rc)%10 and wraps — de-aliases the 32 per-XCD streams across L2 sets
// (stride 3.2768 MB ≡ set-offset 1024: unrotated, all streams alias to 2 set
// positions; rotated, 10 positions x 320 sets cover all 2048).
__global__ __launch_bounds__(320, 1) void k_ffn1(const float* __restrict__ tws,
                                                 const float* __restrict__ w1,
                                                 float* __restrict__ hpart,
                                                 const int* __restrict__ counts,
                                                 const int* __restrict__ list) {
    const int rc = blockIdx.x;
    const int e = blockIdx.y;
    const int cnt = counts[e];
    const int tid = threadIdx.x;
    const int wid = tid >> 6;
    const int lane = tid & 63;
    const int col0 = wid * 256 + lane * 4;   // 0..1279
    const int d0 = rc * RLEN;
    const int t0 = (3 * e + 7 * rc) % 10;

    __shared__ float wlds[2][8 * TWO_I];   // 2 x 40 KB
    __shared__ float tl[CHUNK][RLEN];      // 5 KB

    const float* wpanel = w1 + (size_t)e * DDIM * TWO_I + (size_t)d0 * TWO_I;

    for (int c0 = 0; c0 < cnt; c0 += CHUNK) {
        int pid[CHUNK];
#pragma unroll
        for (int s = 0; s < CHUNK; ++s) {
            int ii = c0 + s;
            ii = (ii < cnt) ? ii : c0;  // pad: duplicate math, duplicate same-value store
            pid[s] = list[e * NTOK + ii];
        }
        __syncthreads();   // previous pass fully done before tl overwrite
#pragma unroll
        for (int s = 0; s < CHUNK; ++s)
            for (int d = tid; d < RLEN; d += 320)
                tl[s][d] = tws[(pid[s] >> 2) * DDIM + d0 + d];
        __syncthreads();

        float acc[CHUNK][4];
#pragma unroll
        for (int s = 0; s < CHUNK; ++s)
#pragma unroll
            for (int c = 0; c < 4; ++c) acc[s][c] = 0.f;

        {
            const float* g0 = wpanel + (size_t)t0 * 8 * TWO_I;
#pragma unroll
            for (int k = 0; k < 8; ++k)
                GLL(g0 + wid * 2048 + k * 256 + lane * 4, &wlds[0][wid * 2048 + k * 256]);
        }

        for (int i = 0; i < 10; ++i) {
            const int cur = i & 1;
            int tt = t0 + i; if (tt >= 10) tt -= 10;
            if (i + 1 < 10) {
                int tn = t0 + i + 1; if (tn >= 10) tn -= 10;
                const int nxt = cur ^ 1;
                const float* gsrc = wpanel + (size_t)tn * 8 * TWO_I;
#pragma unroll
                for (int k = 0; k < 8; ++k)
                    GLL(gsrc + wid * 2048 + k * 256 + lane * 4, &wlds[nxt][wid * 2048 + k * 256]);
                WAITVM(8);
            } else {
                WAITVM(0);
            }
            RAWBAR();
#pragma unroll
            for (int r = 0; r < 8; ++r) {
                const float4 w = *reinterpret_cast<const float4*>(&wlds[cur][r * TWO_I + col0]);
                const int row = tt * 8 + r;
#pragma unroll
                for (int s = 0; s < CHUNK; ++s) {
                    const float tv = tl[s][row];
                    acc[s][0] = fmaf(tv, w.x, acc[s][0]);
                    acc[s][1] = fmaf(tv, w.y, acc[s][1]);
                    acc[s][2] = fmaf(tv, w.z, acc[s][2]);
                    acc[s][3] = fmaf(tv, w.w, acc[s][3]);
                }
            }
            RAWBAR();
        }

#pragma unroll
        for (int s = 0; s < CHUNK; ++s) {
            float4 v = make_float4(acc[s][0], acc[s][1], acc[s][2], acc[s][3]);
            *reinterpret_cast<float4*>(&hpart[((size_t)rc * NPAIR + pid[s]) * TWO_I + col0]) = v;
        }
    }
}

// grid (256) x 256: reduce rc partials, add bias, activation -> hact
__global__ void k_reduce1(const float* __restrict__ hpart, const float* __restrict__ b1,
                          const int* __restrict__ pexp, float* __restrict__ hact) {
    const int p = blockIdx.x;
    const int e = pexp[p];
    for (int i = threadIdx.x; i < IDIM; i += 256) {
        float g = 0.f, l = 0.f;
#pragma unroll
        for (int rc = 0; rc < RC; ++rc) {
            g += hpart[((size_t)rc * NPAIR + p) * TWO_I + i];
            l += hpart[((size_t)rc * NPAIR + p) * TWO_I + i + IDIM];
        }
        float hg = fminf(g + b1[e * TWO_I + i], LIMIT);
        float hl = l + b1[e * TWO_I + IDIM + i];
        hl = fminf(fmaxf(hl, -LIMIT), LIMIT);
        const float sig = 1.0f / (1.0f + __expf(-1.702f * hg));
        hact[(size_t)p * IDIM + i] = hg * sig * (hl + 1.0f);
    }
}

// grid (RC=8, NEXP=32): same rotation over w2's 5 tiles (t0=(2e+rc)%5).
__global__ __launch_bounds__(320, 1) void k_ffn2(const float* __restrict__ hact,
                                                 const float* __restrict__ w2,
                                                 float* __restrict__ hpart2,
                                                 const int* __restrict__ counts,
                                                 const int* __restrict__ list) {
    const int rc = blockIdx.x;
    const int e = blockIdx.y;
    const int cnt = counts[e];
    const int tid = threadIdx.x;
    const int wid = tid >> 6;
    const int lane = tid & 63;
    const int col0 = tid * 2;                // 0..638
    const int i0 = rc * RLEN;
    const int t0 = (2 * e + rc) % 5;

    __shared__ float wlds[2][16 * DDIM];   // 2 x 40 KB
    __shared__ float tl[CHUNK][RLEN];

    const float* wpanel = w2 + (size_t)e * IDIM * DDIM + (size_t)i0 * DDIM;

    for (int c0 = 0; c0 < cnt; c0 += CHUNK) {
        int pid[CHUNK];
#pragma unroll
        for (int s = 0; s < CHUNK; ++s) {
            int ii = c0 + s;
            ii = (ii < cnt) ? ii : c0;
            pid[s] = list[e * NTOK + ii];
        }
        __syncthreads();
#pragma unroll
        for (int s = 0; s < CHUNK; ++s)
            for (int d = tid; d < RLEN; d += 320)
                tl[s][d] = hact[(size_t)pid[s] * IDIM + i0 + d];
        __syncthreads();

        float acc[CHUNK][2];
#pragma unroll
        for (int s = 0; s < CHUNK; ++s) { acc[s][0] = 0.f; acc[s][1] = 0.f; }

        {
            const float* g0 = wpanel + (size_t)t0 * 16 * DDIM;
#pragma unroll
            for (int k = 0; k < 8; ++k)
                GLL(g0 + wid * 2048 + k * 256 + lane * 4, &wlds[0][wid * 2048 + k * 256]);
        }

        for (int i = 0; i < 5; ++i) {
            const int cur = i & 1;
            int tt = t0 + i; if (tt >= 5) tt -= 5;
            if (i + 1 < 5) {
                int tn = t0 + i + 1; if (tn >= 5) tn -= 5;
                const int nxt = cur ^ 1;
                const float* gsrc = wpanel + (size_t)tn * 16 * DDIM;
#pragma unroll
                for (int k = 0; k < 8; ++k)
                    GLL(gsrc + wid * 2048 + k * 256 + lane * 4, &wlds[nxt][wid * 2048 + k * 256]);
                WAITVM(8);
            } else {
                WAITVM(0);
            }
            RAWBAR();
#pragma unroll
            for (int r = 0; r < 16; ++r) {
                const float2 w = *reinterpret_cast<const float2*>(&wlds[cur][r * DDIM + col0]);
                const int row = tt * 16 + r;
#pragma unroll
                for (int s = 0; s < CHUNK; ++s) {
                    const float hv = tl[s][row];
                    acc[s][0] = fmaf(hv, w.x, acc[s][0]);
                    acc[s][1] = fmaf(hv, w.y, acc[s][1]);
                }
            }
            RAWBAR();
        }

#pragma unroll
        for (int s = 0; s < CHUNK; ++s) {
            float2 v = make_float2(acc[s][0], acc[s][1]);
            *reinterpret_cast<float2*>(&hpart2[((size_t)rc * NPAIR + pid[s]) * DDIM + col0]) = v;
        }
    }
}

// grid (64) x 256: reduce rc partials of ffn2, add bias, weight by ew, sum k, residual
__global__ void k_final(const float* __restrict__ x, const float* __restrict__ hpart2,
                        const float* __restrict__ b2, const float* __restrict__ ew,
                        const int* __restrict__ pexp, float* __restrict__ out) {
    const int t = blockIdx.x;
    for (int d = threadIdx.x; d < DDIM; d += 256) {
        float v = x[d * NTOK + t];
#pragma unroll
        for (int k = 0; k < KSEL; ++k) {
            const int p = t * KSEL + k;
            const int e = pexp[p];
            float s = 0.f;
#pragma unroll
            for (int rc = 0; rc < RC; ++rc)
                s += hpart2[((size_t)rc * NPAIR + p) * DDIM + d];
            v += (s + b2[e * DDIM + d]) * ew[p];
        }
        out[d * NTOK + t] = v;
    }
}

extern "C" void kernel_launch(void* const* d_in, const int* in_sizes, int n_in,
                              void* d_out, int out_size, void* d_ws, size_t ws_size,
                              hipStream_t stream) {
    const float* x  = (const float*)d_in[0];
    const float* nw = (const float*)d_in[1];
    const float* gw = (const float*)d_in[2];
    const float* gb = (const float*)d_in[3];
    const float* w1 = (const float*)d_in[4];
    const float* b1 = (const float*)d_in[5];
    const float* w2 = (const float*)d_in[6];
    const float* b2 = (const float*)d_in[7];
    float* out = (float*)d_out;

    float* ws    = (float*)d_ws;
    float* tws   = ws;                    // 40960
    float* hact  = ws + 40960;            // 163840
    float* hpart = ws + 204800;           // 2621440 (ffn1), reused for ffn2
    float* ew    = ws + 2826240;          // 256
    int* counts  = (int*)(ws + 2826496);  // 32
    int* list    = (int*)(ws + 2826528);  // 2048
    int* pexp    = (int*)(ws + 2828576);  // 256

    hipLaunchKernelGGL(k_rmsnorm, dim3(NTOK), dim3(256), 0, stream, x, nw, tws, counts);
    hipLaunchKernelGGL(k_router, dim3(NTOK), dim3(64), 0, stream, tws, gw, gb, ew, counts, list, pexp);
    hipLaunchKernelGGL(k_ffn1, dim3(RC, NEXP), dim3(320), 0, stream, tws, w1, hpart, counts, list);
    hipLaunchKernelGGL(k_reduce1, dim3(NPAIR), dim3(256), 0, stream, hpart, b1, pexp, hact);
    hipLaunchKernelGGL(k_ffn2, dim3(RC, NEXP), dim3(320), 0, stream, hact, w2, hpart, counts, list);
    hipLaunchKernelGGL(k_final, dim3(NTOK), dim3(256), 0, stream, x, hpart, b2, ew, pexp, out);
}